// Round 1
// baseline (638.659 us; speedup 1.0000x reference)
//
#include <hip/hip_runtime.h>
#include <hip/hip_bf16.h>
#include <stdint.h>

typedef __attribute__((ext_vector_type(8))) short short8;
typedef __attribute__((ext_vector_type(4))) float floatx4;

__device__ __forceinline__ float b2f(unsigned short u) {
    union { unsigned int i; float f; } x; x.i = ((unsigned int)u) << 16; return x.f;
}
__device__ __forceinline__ unsigned short f2b(float f) {
    unsigned int x = __float_as_uint(f);
    return (unsigned short)((x + 0x7FFFu + ((x >> 16) & 1u)) >> 16);
}

__device__ __forceinline__ float ldf(const float* p) { return *p; }
__device__ __forceinline__ float ldf(const unsigned short* p) { return b2f(*p); }

// ---------------- cast f32 -> bf16 (elementwise) ----------------
__global__ void cast_kernel(const float* __restrict__ in, unsigned short* __restrict__ out, int n) {
    int i = (blockIdx.x * blockDim.x + threadIdx.x) * 4;
    if (i + 3 < n) {
        float4 v = *reinterpret_cast<const float4*>(in + i);
        out[i + 0] = f2b(v.x);
        out[i + 1] = f2b(v.y);
        out[i + 2] = f2b(v.z);
        out[i + 3] = f2b(v.w);
    }
}

// ---------------- transpose [R][C] -> bf16 [C][R] ----------------
template<typename T>
__global__ void transpose_to_bf16(const T* __restrict__ in, unsigned short* __restrict__ out,
                                  int R, int C) {
    __shared__ float tile[64][65];
    int tx = threadIdx.x & 63, ty = threadIdx.x >> 6; // ty in 0..3
    int c0 = blockIdx.x * 64, r0 = blockIdx.y * 64;
    #pragma unroll
    for (int i = 0; i < 64; i += 4)
        tile[ty + i][tx] = ldf(&in[(size_t)(r0 + ty + i) * C + c0 + tx]);
    __syncthreads();
    #pragma unroll
    for (int i = 0; i < 64; i += 4)
        out[(size_t)(c0 + ty + i) * R + r0 + tx] = f2b(tile[tx][ty + i]);
}

// ---------------- GEMM: C[M][N] = A[M][K](bf16) @ B, B given as BT[N][K](bf16) ----------------
// block = 256 threads = 4 waves; block tile 64(M)x64(N); wave tile 16x64.
// Fragment layout (verified m92/m97): A row=l&15, k=(l>>4)*8+e ; B col=l&15, k=(l>>4)*8+e ;
// D col=l&15, row=(l>>4)*4+reg (m89/m91).
template<int OF32>
__global__ void gemm_bt(const unsigned short* __restrict__ A, const unsigned short* __restrict__ BT,
                        void* __restrict__ Cout, int M, int N, int K) {
    int l = threadIdx.x & 63, w = threadIdx.x >> 6;
    int nb = blockIdx.x * 64, mb = blockIdx.y * 64;
    int lr = l & 15, lg = l >> 4;
    int mrow = mb + w * 16 + lr;

    floatx4 acc0 = (floatx4)(0.f), acc1 = (floatx4)(0.f), acc2 = (floatx4)(0.f), acc3 = (floatx4)(0.f);

    const short8* ap  = reinterpret_cast<const short8*>(A  + (size_t)mrow * K + lg * 8);
    const short8* bp0 = reinterpret_cast<const short8*>(BT + (size_t)(nb +  0 + lr) * K + lg * 8);
    const short8* bp1 = reinterpret_cast<const short8*>(BT + (size_t)(nb + 16 + lr) * K + lg * 8);
    const short8* bp2 = reinterpret_cast<const short8*>(BT + (size_t)(nb + 32 + lr) * K + lg * 8);
    const short8* bp3 = reinterpret_cast<const short8*>(BT + (size_t)(nb + 48 + lr) * K + lg * 8);

    for (int kb = 0; kb < K; kb += 32) {
        short8 af = *ap; ap += 4;
        acc0 = __builtin_amdgcn_mfma_f32_16x16x32_bf16(af, *bp0, acc0, 0, 0, 0); bp0 += 4;
        acc1 = __builtin_amdgcn_mfma_f32_16x16x32_bf16(af, *bp1, acc1, 0, 0, 0); bp1 += 4;
        acc2 = __builtin_amdgcn_mfma_f32_16x16x32_bf16(af, *bp2, acc2, 0, 0, 0); bp2 += 4;
        acc3 = __builtin_amdgcn_mfma_f32_16x16x32_bf16(af, *bp3, acc3, 0, 0, 0); bp3 += 4;
    }

    int orow = mb + w * 16 + lg * 4;
    if (OF32) {
        float* C = (float*)Cout;
        #pragma unroll
        for (int r = 0; r < 4; ++r) {
            C[(size_t)(orow + r) * N + nb +  0 + lr] = acc0[r];
            C[(size_t)(orow + r) * N + nb + 16 + lr] = acc1[r];
            C[(size_t)(orow + r) * N + nb + 32 + lr] = acc2[r];
            C[(size_t)(orow + r) * N + nb + 48 + lr] = acc3[r];
        }
    } else {
        unsigned short* C = (unsigned short*)Cout;
        #pragma unroll
        for (int r = 0; r < 4; ++r) {
            C[(size_t)(orow + r) * N + nb +  0 + lr] = f2b(acc0[r]);
            C[(size_t)(orow + r) * N + nb + 16 + lr] = f2b(acc1[r]);
            C[(size_t)(orow + r) * N + nb + 32 + lr] = f2b(acc2[r]);
            C[(size_t)(orow + r) * N + nb + 48 + lr] = f2b(acc3[r]);
        }
    }
}

// ---------------- RoPE (in-place on bf16 proj), one thread per (s, head, i<32) ----------------
__global__ void rope_kernel(unsigned short* __restrict__ x, const int* __restrict__ pos_ids,
                            int H, int stride, float scale) {
    int idx = blockIdx.x * blockDim.x + threadIdx.x;
    int i = idx & 31;
    int h = (idx >> 5) % H;
    int s = idx / (32 * H);
    unsigned short* p = x + (size_t)s * stride + h * 64;
    float x1 = b2f(p[i]), x2 = b2f(p[i + 32]);
    float pos = (float)pos_ids[s];
    float inv = powf(10000.0f, -(float)i * (1.0f / 32.0f));
    float a = pos * inv;
    float sn, cs;
    sincosf(a, &sn, &cs);
    p[i]      = f2b((x1 * cs - x2 * sn) * scale);
    p[i + 32] = f2b((x2 * cs + x1 * sn) * scale);
}

// ---------------- causal GQA flash attention ----------------
// 1 wave per (head, 16-row Q tile). KV tiles of 32. Q pre-scaled by 1/8.
// Q: [S][2048] bf16 (rope'd), Kr: [S][512] bf16 (rope'd), VT: [512][S] bf16, O: [S][2048] bf16.
__global__ void attn_kernel(const unsigned short* __restrict__ Q,
                            const unsigned short* __restrict__ Kr,
                            const unsigned short* __restrict__ VT,
                            unsigned short* __restrict__ O) {
    const int S = 2048, HID = 2048, KVW = 512;
    int l = threadIdx.x & 63, w = threadIdx.x >> 6;
    int wave = blockIdx.x * 4 + w;
    int qt = wave & 127;       // 128 q-tiles
    int h = wave >> 7;         // 32 heads
    int lr = l & 15, lg = l >> 4;
    int kvh = h >> 2;

    __shared__ __align__(16) unsigned short P[4][16][32];

    int qrow = qt * 16 + lr;
    const short8* qp = reinterpret_cast<const short8*>(Q + (size_t)qrow * HID + h * 64 + lg * 8);
    short8 qf0 = qp[0];
    short8 qf1 = qp[4]; // +32 elements

    floatx4 acc0 = (floatx4)(0.f), acc1 = (floatx4)(0.f), acc2 = (floatx4)(0.f), acc3 = (floatx4)(0.f);
    float m_run[4] = {-1e30f, -1e30f, -1e30f, -1e30f};
    float l_run[4] = {0.f, 0.f, 0.f, 0.f};

    int ktmax = (qt * 16 + 15) >> 5;
    for (int kt = 0; kt <= ktmax; ++kt) {
        int c0 = kt * 32;
        const unsigned short* ka = Kr + (size_t)(c0 + lr) * KVW + kvh * 64 + lg * 8;
        const unsigned short* kb = ka + 16 * KVW;
        short8 kf0a = *reinterpret_cast<const short8*>(ka);
        short8 kf1a = *reinterpret_cast<const short8*>(ka + 32);
        short8 kf0b = *reinterpret_cast<const short8*>(kb);
        short8 kf1b = *reinterpret_cast<const short8*>(kb + 32);

        floatx4 s0 = (floatx4)(0.f), s1 = (floatx4)(0.f);
        s0 = __builtin_amdgcn_mfma_f32_16x16x32_bf16(qf0, kf0a, s0, 0, 0, 0);
        s0 = __builtin_amdgcn_mfma_f32_16x16x32_bf16(qf1, kf1a, s0, 0, 0, 0);
        s1 = __builtin_amdgcn_mfma_f32_16x16x32_bf16(qf0, kf0b, s1, 0, 0, 0);
        s1 = __builtin_amdgcn_mfma_f32_16x16x32_bf16(qf1, kf1b, s1, 0, 0, 0);

        int col0 = c0 + lr, col1 = col0 + 16;
        float p0[4], p1[4], al[4];
        #pragma unroll
        for (int r = 0; r < 4; ++r) {
            int row = qt * 16 + lg * 4 + r;
            float v0 = (col0 > row) ? -1e30f : s0[r];
            float v1 = (col1 > row) ? -1e30f : s1[r];
            float tm = fmaxf(v0, v1);
            #pragma unroll
            for (int off = 1; off <= 8; off <<= 1) tm = fmaxf(tm, __shfl_xor(tm, off));
            float mn = fmaxf(m_run[r], tm);
            float a = expf(m_run[r] - mn);
            float e0 = expf(v0 - mn);
            float e1 = expf(v1 - mn);
            float rs = e0 + e1;
            #pragma unroll
            for (int off = 1; off <= 8; off <<= 1) rs += __shfl_xor(rs, off);
            m_run[r] = mn;
            l_run[r] = l_run[r] * a + rs;
            al[r] = a; p0[r] = e0; p1[r] = e1;
        }

        #pragma unroll
        for (int r = 0; r < 4; ++r) {
            P[w][lg * 4 + r][lr]      = f2b(p0[r]);
            P[w][lg * 4 + r][lr + 16] = f2b(p1[r]);
            acc0[r] *= al[r]; acc1[r] *= al[r]; acc2[r] *= al[r]; acc3[r] *= al[r];
        }

        // same-wave LDS write->read: DS ops in-order within a wave, no barrier needed
        short8 pf = *reinterpret_cast<const short8*>(&P[w][lr][lg * 8]);

        const short8* v0p = reinterpret_cast<const short8*>(VT + (size_t)(kvh * 64 +  0 + lr) * S + c0 + lg * 8);
        const short8* v1p = reinterpret_cast<const short8*>(VT + (size_t)(kvh * 64 + 16 + lr) * S + c0 + lg * 8);
        const short8* v2p = reinterpret_cast<const short8*>(VT + (size_t)(kvh * 64 + 32 + lr) * S + c0 + lg * 8);
        const short8* v3p = reinterpret_cast<const short8*>(VT + (size_t)(kvh * 64 + 48 + lr) * S + c0 + lg * 8);
        acc0 = __builtin_amdgcn_mfma_f32_16x16x32_bf16(pf, *v0p, acc0, 0, 0, 0);
        acc1 = __builtin_amdgcn_mfma_f32_16x16x32_bf16(pf, *v1p, acc1, 0, 0, 0);
        acc2 = __builtin_amdgcn_mfma_f32_16x16x32_bf16(pf, *v2p, acc2, 0, 0, 0);
        acc3 = __builtin_amdgcn_mfma_f32_16x16x32_bf16(pf, *v3p, acc3, 0, 0, 0);
    }

    #pragma unroll
    for (int r = 0; r < 4; ++r) {
        int row = qt * 16 + lg * 4 + r;
        float inv = 1.0f / l_run[r];
        O[(size_t)row * HID + h * 64 +  0 + lr] = f2b(acc0[r] * inv);
        O[(size_t)row * HID + h * 64 + 16 + lr] = f2b(acc1[r] * inv);
        O[(size_t)row * HID + h * 64 + 32 + lr] = f2b(acc2[r] * inv);
        O[(size_t)row * HID + h * 64 + 48 + lr] = f2b(acc3[r] * inv);
    }
}

extern "C" void kernel_launch(void* const* d_in, const int* in_sizes, int n_in,
                              void* d_out, int out_size, void* d_ws, size_t ws_size,
                              hipStream_t stream) {
    const int S = 2048, HID = 2048, KVD = 512;
    const float* hs = (const float*)d_in[0];
    const float* Wq = (const float*)d_in[1];
    const float* Wk = (const float*)d_in[2];
    const float* Wv = (const float*)d_in[3];
    const float* Wo = (const float*)d_in[4];
    const int* pos  = (const int*)d_in[5];

    char* base = (char*)d_ws;
    auto alloc = [&](size_t bytes) {
        char* r = base;
        base += (bytes + 255) & ~(size_t)255;
        return r;
    };
    unsigned short* hs_b     = (unsigned short*)alloc((size_t)S * HID * 2);
    unsigned short* WqT      = (unsigned short*)alloc((size_t)HID * HID * 2);
    unsigned short* WoT      = (unsigned short*)alloc((size_t)HID * HID * 2);
    unsigned short* WkT      = (unsigned short*)alloc((size_t)KVD * HID * 2);
    unsigned short* WvT      = (unsigned short*)alloc((size_t)KVD * HID * 2);
    unsigned short* q_proj   = (unsigned short*)alloc((size_t)S * HID * 2);
    unsigned short* k_proj   = (unsigned short*)alloc((size_t)S * KVD * 2);
    unsigned short* v_proj   = (unsigned short*)alloc((size_t)S * KVD * 2);
    unsigned short* vT       = (unsigned short*)alloc((size_t)KVD * S * 2);
    unsigned short* attn_out = (unsigned short*)alloc((size_t)S * HID * 2);

    // 1. cast hidden_states f32 -> bf16
    cast_kernel<<<(S * HID / 4 + 255) / 256, 256, 0, stream>>>(hs, hs_b, S * HID);

    // 2. transpose weights to [N][K] bf16
    transpose_to_bf16<float><<<dim3(HID / 64, HID / 64), 256, 0, stream>>>(Wq, WqT, HID, HID);
    transpose_to_bf16<float><<<dim3(KVD / 64, HID / 64), 256, 0, stream>>>(Wk, WkT, HID, KVD);
    transpose_to_bf16<float><<<dim3(KVD / 64, HID / 64), 256, 0, stream>>>(Wv, WvT, HID, KVD);
    transpose_to_bf16<float><<<dim3(HID / 64, HID / 64), 256, 0, stream>>>(Wo, WoT, HID, HID);

    // 3. QKV projections (bf16 out)
    gemm_bt<0><<<dim3(HID / 64, S / 64), 256, 0, stream>>>(hs_b, WqT, q_proj, S, HID, HID);
    gemm_bt<0><<<dim3(KVD / 64, S / 64), 256, 0, stream>>>(hs_b, WkT, k_proj, S, KVD, HID);
    gemm_bt<0><<<dim3(KVD / 64, S / 64), 256, 0, stream>>>(hs_b, WvT, v_proj, S, KVD, HID);

    // 4. RoPE (q scaled by 1/sqrt(64))
    rope_kernel<<<(S * 32 * 32) / 256, 256, 0, stream>>>(q_proj, pos, 32, HID, 0.125f);
    rope_kernel<<<(S * 8 * 32) / 256, 256, 0, stream>>>(k_proj, pos, 8, KVD, 1.0f);

    // 5. V^T for PV fragments
    transpose_to_bf16<unsigned short><<<dim3(KVD / 64, S / 64), 256, 0, stream>>>(v_proj, vT, S, KVD);

    // 6. attention (32 heads x 128 q-tiles = 4096 waves, 4 waves/block)
    attn_kernel<<<(32 * 128) / 4, 256, 0, stream>>>(q_proj, k_proj, vT, attn_out);

    // 7. output projection -> f32 d_out
    gemm_bt<1><<<dim3(HID / 64, S / 64), 256, 0, stream>>>(attn_out, WoT, (float*)d_out, S, HID, HID);
}

// Round 2
// 280.416 us; speedup vs baseline: 2.2775x; 2.2775x over previous
//
#include <hip/hip_runtime.h>
#include <stdint.h>

typedef __attribute__((ext_vector_type(8))) short short8;
typedef __attribute__((ext_vector_type(4))) float floatx4;

__device__ __forceinline__ float b2f(unsigned short u) {
    union { unsigned int i; float f; } x; x.i = ((unsigned int)u) << 16; return x.f;
}
__device__ __forceinline__ unsigned short f2b(float f) {
    unsigned int x = __float_as_uint(f);
    return (unsigned short)((x + 0x7FFFu + ((x >> 16) & 1u)) >> 16);
}
// pack two f32 -> (bf16(hi)<<16)|bf16(lo), RTNE, one instruction
__device__ __forceinline__ unsigned int cvt_pk_bf16(float lo, float hi) {
    unsigned int r;
    asm("v_cvt_pk_bf16_f32 %0, %1, %2" : "=v"(r) : "v"(lo), "v"(hi));
    return r;
}

__device__ __forceinline__ float ldf(const float* p) { return *p; }
__device__ __forceinline__ float ldf(const unsigned short* p) { return b2f(*p); }

__device__ __forceinline__ void gload_lds16(const void* g, void* l) {
    __builtin_amdgcn_global_load_lds((const __attribute__((address_space(1))) unsigned int*)g,
                                     (__attribute__((address_space(3))) unsigned int*)l, 16, 0, 0);
}

// ---------------- cast f32 -> bf16 ----------------
__global__ void cast_kernel(const float* __restrict__ in, unsigned short* __restrict__ out, int n) {
    int i = (blockIdx.x * blockDim.x + threadIdx.x) * 4;
    if (i + 3 < n) {
        float4 v = *reinterpret_cast<const float4*>(in + i);
        out[i + 0] = f2b(v.x);
        out[i + 1] = f2b(v.y);
        out[i + 2] = f2b(v.z);
        out[i + 3] = f2b(v.w);
    }
}

// ---------------- transpose: out[c][r] = in[r][c], bf16 out, strided ----------------
template<typename T>
__global__ void transpose_to_bf16(const T* __restrict__ in, unsigned short* __restrict__ out,
                                  int ld_in, int ld_out) {
    __shared__ float tile[64][65];
    int tx = threadIdx.x & 63, ty = threadIdx.x >> 6; // ty 0..3
    int c0 = blockIdx.x * 64, r0 = blockIdx.y * 64;
    #pragma unroll
    for (int i = 0; i < 64; i += 4)
        tile[ty + i][tx] = ldf(&in[(size_t)(r0 + ty + i) * ld_in + c0 + tx]);
    __syncthreads();
    #pragma unroll
    for (int i = 0; i < 64; i += 4)
        out[(size_t)(c0 + ty + i) * ld_out + r0 + tx] = f2b(tile[tx][ty + i]);
}

// ---------------- GEMM m97-structure: C[M][N] = A[M][K] @ BT[N][K]^T ----------------
// 128x128 tile, BK=32, 256 thr (4 waves, 2x2 wave grid, 64x64/wave = 4x4 16x16 frags).
// global_load_lds(16B) staging, linear LDS, 2 barriers/K-step.
template<int OF32>
__global__ __launch_bounds__(256)
void gemm128(const unsigned short* __restrict__ A, const unsigned short* __restrict__ BT,
             void* __restrict__ Cout, int M, int N, int K) {
    __shared__ unsigned short As[128 * 32];
    __shared__ unsigned short Bs[128 * 32];
    int tid = threadIdx.x;
    int l = tid & 63, w = tid >> 6;
    int lr = l & 15, lg = l >> 4;
    int nb = blockIdx.x * 128, mb = blockIdx.y * 128;
    int wr = w >> 1, wc = w & 1;

    floatx4 acc[4][4];
    #pragma unroll
    for (int m = 0; m < 4; ++m)
        #pragma unroll
        for (int n = 0; n < 4; ++n) acc[m][n] = (floatx4)(0.f);

    // staging chunks: c = w*64 + l (+256); chunk c -> row c>>2, col8 (c&3)*8
    int c0i = w * 64 + l;
    int c1i = c0i + 256;
    int r0 = c0i >> 2, k0 = (c0i & 3) * 8;
    int r1 = c1i >> 2, k1 = (c1i & 3) * 8;

    const unsigned short* Ag0 = A + (size_t)(mb + r0) * K + k0;
    const unsigned short* Ag1 = A + (size_t)(mb + r1) * K + k1;
    const unsigned short* Bg0 = BT + (size_t)(nb + r0) * K + k0;
    const unsigned short* Bg1 = BT + (size_t)(nb + r1) * K + k1;
    unsigned short* Al0 = As + c0i * 8;
    unsigned short* Al1 = As + c1i * 8;
    unsigned short* Bl0 = Bs + c0i * 8;
    unsigned short* Bl1 = Bs + c1i * 8;

    const unsigned short* ArdA = As + (wr * 64 + lr) * 32 + lg * 8;
    const unsigned short* BrdB = Bs + (wc * 64 + lr) * 32 + lg * 8;

    for (int kb = 0; kb < K; kb += 32) {
        gload_lds16(Ag0 + kb, Al0);
        gload_lds16(Ag1 + kb, Al1);
        gload_lds16(Bg0 + kb, Bl0);
        gload_lds16(Bg1 + kb, Bl1);
        __syncthreads(); // drains vmcnt -> staged data visible

        short8 af[4], bf[4];
        #pragma unroll
        for (int m = 0; m < 4; ++m) af[m] = *reinterpret_cast<const short8*>(ArdA + m * 16 * 32);
        #pragma unroll
        for (int n = 0; n < 4; ++n) bf[n] = *reinterpret_cast<const short8*>(BrdB + n * 16 * 32);
        #pragma unroll
        for (int m = 0; m < 4; ++m)
            #pragma unroll
            for (int n = 0; n < 4; ++n)
                acc[m][n] = __builtin_amdgcn_mfma_f32_16x16x32_bf16(af[m], bf[n], acc[m][n], 0, 0, 0);
        __syncthreads(); // protect LDS before next stage
    }

    int orow0 = mb + wr * 64 + lg * 4;
    int ocol0 = nb + wc * 64 + lr;
    if (OF32) {
        float* C = (float*)Cout;
        #pragma unroll
        for (int m = 0; m < 4; ++m)
            #pragma unroll
            for (int n = 0; n < 4; ++n)
                #pragma unroll
                for (int r = 0; r < 4; ++r)
                    C[(size_t)(orow0 + m * 16 + r) * N + ocol0 + n * 16] = acc[m][n][r];
    } else {
        unsigned short* C = (unsigned short*)Cout;
        #pragma unroll
        for (int m = 0; m < 4; ++m)
            #pragma unroll
            for (int n = 0; n < 4; ++n)
                #pragma unroll
                for (int r = 0; r < 4; ++r)
                    C[(size_t)(orow0 + m * 16 + r) * N + ocol0 + n * 16] = f2b(acc[m][n][r]);
    }
}

// ---------------- RoPE in-place, one thread per (s, head, i<32) ----------------
__global__ void rope_kernel(unsigned short* __restrict__ x, const int* __restrict__ pos_ids,
                            int H, int stride, float scale) {
    int idx = blockIdx.x * blockDim.x + threadIdx.x;
    int i = idx & 31;
    int h = (idx >> 5) % H;
    int s = idx / (32 * H);
    unsigned short* p = x + (size_t)s * stride + h * 64;
    float x1 = b2f(p[i]), x2 = b2f(p[i + 32]);
    float pos = (float)pos_ids[s];
    // theta^(-i/32) = exp2(-i * log2(1e4)/32)
    float inv = exp2f(-0.41524101186092029f * (float)i);
    float a = pos * inv;
    float sn, cs;
    __sincosf(a, &sn, &cs);
    p[i]      = f2b((x1 * cs - x2 * sn) * scale);
    p[i + 32] = f2b((x2 * cs + x1 * sn) * scale);
}

// ---------------- causal GQA flash attention, swapped-operand, no LDS ----------------
// 1 wave per (head, 16 q-rows); each lane owns ONE q-row (q = qt*16 + (l&15)).
// KVBLK=64. S^T = mfma(K, Q): lane(l) holds S^T[k = c0+16t+4g+r][q=lr], g=l>>4.
// PV as O^T = V^T P^T; P^T B-frags built via cvt_pk + 16 shuffles (lane-group exchange).
__global__ __launch_bounds__(256)
void attn_kernel(const unsigned short* __restrict__ QKV, // [2048][3072] bf16 (q|k|v)
                 const unsigned short* __restrict__ VT,  // [512][2048]  bf16
                 unsigned short* __restrict__ O) {       // [2048][2048] bf16
    const int S = 2048, LDQ = 3072, HID = 2048;
    int l = threadIdx.x & 63, w = threadIdx.x >> 6;
    int b = blockIdx.x;
    int h = b & 31;
    int qtg = 31 - (b >> 5);          // heavy tiles first (causal load balance)
    int qt = qtg * 4 + w;
    int lr = l & 15, g = l >> 4;
    int kvh = h >> 2;
    int q = qt * 16 + lr;

    const unsigned short* Qrow = QKV + (size_t)q * LDQ + h * 64;
    short8 qf0 = *reinterpret_cast<const short8*>(Qrow + g * 8);       // d 0..31
    short8 qf1 = *reinterpret_cast<const short8*>(Qrow + 32 + g * 8);  // d 32..63

    const unsigned short* Kbase = QKV + 2048 + (size_t)kvh * 64;
    const unsigned short* Vbase = VT + (size_t)(kvh * 64) * S;

    floatx4 acc[4]; // acc[db][r] = O^T[d = db*16 + g*4 + r][q]
    #pragma unroll
    for (int db = 0; db < 4; ++db) acc[db] = (floatx4)(0.f);
    float m_run = -1e30f, l_run = 0.f;

    int src0 = lr + (g & 1) * 32; // lane holding k_sub 8*(g&1)+{0..3}
    int src1 = src0 + 16;         // lane holding k_sub 8*(g&1)+{4..7}
    bool hi_t = (g >> 1) != 0;    // which subtile of the K-step this lane needs

    int nfull = qt >> 2;
    for (int kt = 0; kt <= nfull; ++kt) {
        int c0 = kt * 64;
        bool diag = (kt == nfull);

        // QK^T (swapped): st[t][r] = S^T[k = c0+16t+4g+r][q]
        floatx4 st[4];
        #pragma unroll
        for (int t = 0; t < 4; ++t) {
            const unsigned short* kp = Kbase + (size_t)(c0 + t * 16 + lr) * LDQ + g * 8;
            short8 klo = *reinterpret_cast<const short8*>(kp);
            short8 khi = *reinterpret_cast<const short8*>(kp + 32);
            floatx4 z = (floatx4)(0.f);
            z = __builtin_amdgcn_mfma_f32_16x16x32_bf16(klo, qf0, z, 0, 0, 0);
            z = __builtin_amdgcn_mfma_f32_16x16x32_bf16(khi, qf1, z, 0, 0, 0);
            st[t] = z;
        }

        if (diag) {
            #pragma unroll
            for (int t = 0; t < 4; ++t)
                #pragma unroll
                for (int r = 0; r < 4; ++r) {
                    int kc = c0 + t * 16 + g * 4 + r;
                    if (kc > q) st[t][r] = -1e30f;
                }
        }

        // online softmax: lane-local over 16 regs + 2 shfl_xor across g-groups
        float tm = st[0][0];
        #pragma unroll
        for (int t = 0; t < 4; ++t)
            #pragma unroll
            for (int r = 0; r < 4; ++r) tm = fmaxf(tm, st[t][r]);
        tm = fmaxf(tm, __shfl_xor(tm, 16));
        tm = fmaxf(tm, __shfl_xor(tm, 32));
        float mn = fmaxf(m_run, tm);
        float alpha = __expf(m_run - mn);
        float p[4][4];
        float rs = 0.f;
        #pragma unroll
        for (int t = 0; t < 4; ++t)
            #pragma unroll
            for (int r = 0; r < 4; ++r) {
                float e = __expf(st[t][r] - mn);
                p[t][r] = e;
                rs += e;
            }
        rs += __shfl_xor(rs, 16);
        rs += __shfl_xor(rs, 32);
        m_run = mn;
        l_run = l_run * alpha + rs;
        #pragma unroll
        for (int db = 0; db < 4; ++db) acc[db] *= alpha;

        // pack P to bf16 pairs per subtile
        unsigned int ulo[4], uhi[4];
        #pragma unroll
        for (int t = 0; t < 4; ++t) {
            ulo[t] = cvt_pk_bf16(p[t][0], p[t][1]);
            uhi[t] = cvt_pk_bf16(p[t][2], p[t][3]);
        }

        // two PV K-steps of 32: build P^T B-frag via lane-group exchange, then 4 MFMA each
        #pragma unroll
        for (int ks = 0; ks < 2; ++ks) {
            unsigned int a0 = __shfl((int)ulo[ks * 2], src0), b0 = __shfl((int)ulo[ks * 2 + 1], src0);
            unsigned int a1 = __shfl((int)uhi[ks * 2], src0), b1 = __shfl((int)uhi[ks * 2 + 1], src0);
            unsigned int a2 = __shfl((int)ulo[ks * 2], src1), b2 = __shfl((int)ulo[ks * 2 + 1], src1);
            unsigned int a3 = __shfl((int)uhi[ks * 2], src1), b3 = __shfl((int)uhi[ks * 2 + 1], src1);
            union { unsigned int u[4]; short8 s; } bfu;
            bfu.u[0] = hi_t ? b0 : a0;
            bfu.u[1] = hi_t ? b1 : a1;
            bfu.u[2] = hi_t ? b2 : a2;
            bfu.u[3] = hi_t ? b3 : a3;
            #pragma unroll
            for (int db = 0; db < 4; ++db) {
                const unsigned short* vp = Vbase + (size_t)(db * 16 + lr) * S + c0 + ks * 32 + g * 8;
                acc[db] = __builtin_amdgcn_mfma_f32_16x16x32_bf16(
                    *reinterpret_cast<const short8*>(vp), bfu.s, acc[db], 0, 0, 0);
            }
        }
    }

    float inv = 1.0f / l_run;
    unsigned short* Op = O + (size_t)q * HID + h * 64;
    #pragma unroll
    for (int db = 0; db < 4; ++db) {
        int d0 = db * 16 + g * 4;
        *reinterpret_cast<unsigned int*>(Op + d0)     = cvt_pk_bf16(acc[db][0] * inv, acc[db][1] * inv);
        *reinterpret_cast<unsigned int*>(Op + d0 + 2) = cvt_pk_bf16(acc[db][2] * inv, acc[db][3] * inv);
    }
}

extern "C" void kernel_launch(void* const* d_in, const int* in_sizes, int n_in,
                              void* d_out, int out_size, void* d_ws, size_t ws_size,
                              hipStream_t stream) {
    const int S = 2048, HID = 2048, KVD = 512, NQKV = 3072;
    const float* hs = (const float*)d_in[0];
    const float* Wq = (const float*)d_in[1];
    const float* Wk = (const float*)d_in[2];
    const float* Wv = (const float*)d_in[3];
    const float* Wo = (const float*)d_in[4];
    const int* pos  = (const int*)d_in[5];

    char* base = (char*)d_ws;
    auto alloc = [&](size_t bytes) {
        char* r = base;
        base += (bytes + 255) & ~(size_t)255;
        return r;
    };
    unsigned short* hs_b     = (unsigned short*)alloc((size_t)S * HID * 2);
    unsigned short* Wqkv     = (unsigned short*)alloc((size_t)NQKV * HID * 2); // [3072][2048] = WqT|WkT|WvT
    unsigned short* WoT      = (unsigned short*)alloc((size_t)HID * HID * 2);
    unsigned short* qkv      = (unsigned short*)alloc((size_t)S * NQKV * 2);   // [2048][3072]
    unsigned short* vT       = (unsigned short*)alloc((size_t)KVD * S * 2);
    unsigned short* attn_out = (unsigned short*)alloc((size_t)S * HID * 2);

    // 1. cast hidden_states f32 -> bf16
    cast_kernel<<<(S * HID / 4 + 255) / 256, 256, 0, stream>>>(hs, hs_b, S * HID);

    // 2. weight transposes into fused [3072][2048] + WoT
    transpose_to_bf16<float><<<dim3(HID / 64, HID / 64), 256, 0, stream>>>(Wq, Wqkv, HID, HID);
    transpose_to_bf16<float><<<dim3(KVD / 64, HID / 64), 256, 0, stream>>>(Wk, Wqkv + (size_t)2048 * HID, KVD, HID);
    transpose_to_bf16<float><<<dim3(KVD / 64, HID / 64), 256, 0, stream>>>(Wv, Wqkv + (size_t)2560 * HID, KVD, HID);
    transpose_to_bf16<float><<<dim3(HID / 64, HID / 64), 256, 0, stream>>>(Wo, WoT, HID, HID);

    // 3. fused QKV projection: [2048][2048] @ [2048][3072] -> [2048][3072]
    gemm128<0><<<dim3(NQKV / 128, S / 128), 256, 0, stream>>>(hs_b, Wqkv, qkv, S, NQKV, HID);

    // 4. RoPE (Q scaled by 1/8)
    rope_kernel<<<(S * 32 * 32) / 256, 256, 0, stream>>>(qkv, pos, 32, NQKV, 0.125f);
    rope_kernel<<<(S * 8 * 32) / 256, 256, 0, stream>>>(qkv + 2048, pos, 8, NQKV, 1.0f);

    // 5. V^T: vT[d][s] = qkv[s][2560 + d]
    transpose_to_bf16<unsigned short><<<dim3(KVD / 64, S / 64), 256, 0, stream>>>(qkv + 2560, vT, NQKV, S);

    // 6. attention: 1024 blocks x 4 waves; block b -> head b&31, q-tiles (31-(b>>5))*4 + w
    attn_kernel<<<1024, 256, 0, stream>>>(qkv, vT, attn_out);

    // 7. output projection -> f32
    gemm128<1><<<dim3(HID / 128, S / 128), 256, 0, stream>>>(attn_out, WoT, (float*)d_out, S, HID, HID);
}

// Round 3
// 193.579 us; speedup vs baseline: 3.2992x; 1.4486x over previous
//
#include <hip/hip_runtime.h>
#include <stdint.h>

typedef __attribute__((ext_vector_type(8))) short short8;
typedef __attribute__((ext_vector_type(4))) float floatx4;

__device__ __forceinline__ float b2f(unsigned short u) {
    union { unsigned int i; float f; } x; x.i = ((unsigned int)u) << 16; return x.f;
}
__device__ __forceinline__ unsigned short f2b(float f) {
    unsigned int x = __float_as_uint(f);
    return (unsigned short)((x + 0x7FFFu + ((x >> 16) & 1u)) >> 16);
}
// pack two f32 -> (bf16(hi)<<16)|bf16(lo), RTNE, one instruction
__device__ __forceinline__ unsigned int cvt_pk_bf16(float lo, float hi) {
    unsigned int r;
    asm("v_cvt_pk_bf16_f32 %0, %1, %2" : "=v"(r) : "v"(lo), "v"(hi));
    return r;
}

__device__ __forceinline__ float ldf(const float* p) { return *p; }
__device__ __forceinline__ float ldf(const unsigned short* p) { return b2f(*p); }

__device__ __forceinline__ void gload_lds16(const void* g, void* l) {
    __builtin_amdgcn_global_load_lds((const __attribute__((address_space(1))) unsigned int*)g,
                                     (__attribute__((address_space(3))) unsigned int*)l, 16, 0, 0);
}

// ---------------- cast f32 -> bf16 ----------------
__global__ void cast_kernel(const float* __restrict__ in, unsigned short* __restrict__ out, int n) {
    int i = (blockIdx.x * blockDim.x + threadIdx.x) * 4;
    if (i + 3 < n) {
        float4 v = *reinterpret_cast<const float4*>(in + i);
        out[i + 0] = f2b(v.x);
        out[i + 1] = f2b(v.y);
        out[i + 2] = f2b(v.z);
        out[i + 3] = f2b(v.w);
    }
}

// ---------------- transpose: out[c][r] = in[r][c], bf16 out, strided ----------------
template<typename T>
__global__ void transpose_to_bf16(const T* __restrict__ in, unsigned short* __restrict__ out,
                                  int ld_in, int ld_out) {
    __shared__ float tile[64][65];
    int tx = threadIdx.x & 63, ty = threadIdx.x >> 6; // ty 0..3
    int c0 = blockIdx.x * 64, r0 = blockIdx.y * 64;
    #pragma unroll
    for (int i = 0; i < 64; i += 4)
        tile[ty + i][tx] = ldf(&in[(size_t)(r0 + ty + i) * ld_in + c0 + tx]);
    __syncthreads();
    #pragma unroll
    for (int i = 0; i < 64; i += 4)
        out[(size_t)(c0 + ty + i) * ld_out + r0 + tx] = f2b(tile[tx][ty + i]);
}

// ---------------- GEMM m97-structure: C[M][N] = A[M][K] @ BT[N][K]^T ----------------
template<int OF32>
__global__ __launch_bounds__(256)
void gemm128(const unsigned short* __restrict__ A, const unsigned short* __restrict__ BT,
             void* __restrict__ Cout, int M, int N, int K) {
    __shared__ unsigned short As[128 * 32];
    __shared__ unsigned short Bs[128 * 32];
    int tid = threadIdx.x;
    int l = tid & 63, w = tid >> 6;
    int lr = l & 15, lg = l >> 4;
    int nb = blockIdx.x * 128, mb = blockIdx.y * 128;
    int wr = w >> 1, wc = w & 1;

    floatx4 acc[4][4];
    #pragma unroll
    for (int m = 0; m < 4; ++m)
        #pragma unroll
        for (int n = 0; n < 4; ++n) acc[m][n] = (floatx4)(0.f);

    int c0i = w * 64 + l;
    int c1i = c0i + 256;
    int r0 = c0i >> 2, k0 = (c0i & 3) * 8;
    int r1 = c1i >> 2, k1 = (c1i & 3) * 8;

    const unsigned short* Ag0 = A + (size_t)(mb + r0) * K + k0;
    const unsigned short* Ag1 = A + (size_t)(mb + r1) * K + k1;
    const unsigned short* Bg0 = BT + (size_t)(nb + r0) * K + k0;
    const unsigned short* Bg1 = BT + (size_t)(nb + r1) * K + k1;
    unsigned short* Al0 = As + c0i * 8;
    unsigned short* Al1 = As + c1i * 8;
    unsigned short* Bl0 = Bs + c0i * 8;
    unsigned short* Bl1 = Bs + c1i * 8;

    const unsigned short* ArdA = As + (wr * 64 + lr) * 32 + lg * 8;
    const unsigned short* BrdB = Bs + (wc * 64 + lr) * 32 + lg * 8;

    for (int kb = 0; kb < K; kb += 32) {
        gload_lds16(Ag0 + kb, Al0);
        gload_lds16(Ag1 + kb, Al1);
        gload_lds16(Bg0 + kb, Bl0);
        gload_lds16(Bg1 + kb, Bl1);
        __syncthreads();

        short8 af[4], bf[4];
        #pragma unroll
        for (int m = 0; m < 4; ++m) af[m] = *reinterpret_cast<const short8*>(ArdA + m * 16 * 32);
        #pragma unroll
        for (int n = 0; n < 4; ++n) bf[n] = *reinterpret_cast<const short8*>(BrdB + n * 16 * 32);
        #pragma unroll
        for (int m = 0; m < 4; ++m)
            #pragma unroll
            for (int n = 0; n < 4; ++n)
                acc[m][n] = __builtin_amdgcn_mfma_f32_16x16x32_bf16(af[m], bf[n], acc[m][n], 0, 0, 0);
        __syncthreads();
    }

    int orow0 = mb + wr * 64 + lg * 4;
    int ocol0 = nb + wc * 64 + lr;
    if (OF32) {
        float* C = (float*)Cout;
        #pragma unroll
        for (int m = 0; m < 4; ++m)
            #pragma unroll
            for (int n = 0; n < 4; ++n)
                #pragma unroll
                for (int r = 0; r < 4; ++r)
                    C[(size_t)(orow0 + m * 16 + r) * N + ocol0 + n * 16] = acc[m][n][r];
    } else {
        unsigned short* C = (unsigned short*)Cout;
        #pragma unroll
        for (int m = 0; m < 4; ++m)
            #pragma unroll
            for (int n = 0; n < 4; ++n)
                #pragma unroll
                for (int r = 0; r < 4; ++r)
                    C[(size_t)(orow0 + m * 16 + r) * N + ocol0 + n * 16] = f2b(acc[m][n][r]);
    }
}

// ---------------- RoPE in-place ----------------
__global__ void rope_kernel(unsigned short* __restrict__ x, const int* __restrict__ pos_ids,
                            int H, int stride, float scale) {
    int idx = blockIdx.x * blockDim.x + threadIdx.x;
    int i = idx & 31;
    int h = (idx >> 5) % H;
    int s = idx / (32 * H);
    unsigned short* p = x + (size_t)s * stride + h * 64;
    float x1 = b2f(p[i]), x2 = b2f(p[i + 32]);
    float pos = (float)pos_ids[s];
    float inv = exp2f(-0.41524101186092029f * (float)i);
    float a = pos * inv;
    float sn, cs;
    __sincosf(a, &sn, &cs);
    p[i]      = f2b((x1 * cs - x2 * sn) * scale);
    p[i + 32] = f2b((x2 * cs + x1 * sn) * scale);
}

// ---------------- causal GQA flash attention v3 ----------------
// Block = 4 waves = 128 q-rows of one head (qb band). Each wave: 32 q-rows (2 frags).
// KV tiles of 64 double-buffered in LDS (K[64][64], VT[64][64] bf16, XOR-swizzled chunks,
// staged by global_load_lds with pre-swizzled global source). Counted vmcnt(4) + raw
// s_barrier keeps next tile's loads in flight across the barrier.
__global__ __launch_bounds__(256)
void attn_kernel(const unsigned short* __restrict__ QKV, // [2048][3072] bf16 (q|k|v)
                 const unsigned short* __restrict__ VT,  // [512][2048]  bf16
                 unsigned short* __restrict__ O) {       // [2048][2048] bf16
    const int S = 2048, LDQ = 3072, HID = 2048;
    __shared__ __align__(16) unsigned short Kl[2][64 * 64];
    __shared__ __align__(16) unsigned short Vl[2][64 * 64];

    int l = threadIdx.x & 63, w = threadIdx.x >> 6;
    int b = blockIdx.x;
    int h = b & 31;
    int qb = 15 - (b >> 5);           // heavy bands first
    int lr = l & 15, g = l >> 4;
    int kvh = h >> 2;
    int q0 = qb * 128 + w * 32 + lr;  // frag A rows; frag B = q0 + 16

    // Q fragments (2 q-tiles x {d0..31, d32..63})
    const unsigned short* Qr0 = QKV + (size_t)q0 * LDQ + h * 64;
    const unsigned short* Qr1 = Qr0 + (size_t)16 * LDQ;
    short8 qA0 = *reinterpret_cast<const short8*>(Qr0 + g * 8);
    short8 qA1 = *reinterpret_cast<const short8*>(Qr0 + 32 + g * 8);
    short8 qB0 = *reinterpret_cast<const short8*>(Qr1 + g * 8);
    short8 qB1 = *reinterpret_cast<const short8*>(Qr1 + 32 + g * 8);

    // staging geometry: chunk c in [0,512): row=c>>3, slot=c&7 holds logical chunk slot^(row&7)
    int c_0 = w * 64 + l, c_1 = c_0 + 256;
    int row0 = c_0 >> 3, lc0 = (c_0 & 7) ^ (row0 & 7);
    int row1 = c_1 >> 3, lc1 = (c_1 & 7) ^ (row1 & 7);
    const unsigned short* Kg = QKV + 2048 + kvh * 64;       // + (c0+row)*LDQ + lc*8
    const unsigned short* Vg = VT + (size_t)(kvh * 64) * S; // + row*S + c0 + lc*8

    floatx4 accA[4], accB[4];
    #pragma unroll
    for (int db = 0; db < 4; ++db) { accA[db] = (floatx4)(0.f); accB[db] = (floatx4)(0.f); }
    float mA = -1e30f, lA = 0.f, mB = -1e30f, lB = 0.f;

    int src0 = lr + (g & 1) * 32;
    int src1 = src0 + 16;
    bool hi_t = (g >> 1) != 0;

    int ktmax_w = 2 * qb + (w >> 1);
    int ktmax_blk = 2 * qb + 1;

    auto stage = [&](int buf, int c0) {
        gload_lds16(Kg + (size_t)(c0 + row0) * LDQ + lc0 * 8, &Kl[buf][c_0 * 8]);
        gload_lds16(Kg + (size_t)(c0 + row1) * LDQ + lc1 * 8, &Kl[buf][c_1 * 8]);
        gload_lds16(Vg + (size_t)row0 * S + c0 + lc0 * 8, &Vl[buf][c_0 * 8]);
        gload_lds16(Vg + (size_t)row1 * S + c0 + lc1 * 8, &Vl[buf][c_1 * 8]);
    };

    stage(0, 0);
    for (int kt = 0; kt <= ktmax_blk; ++kt) {
        int nxt = (kt < ktmax_blk) ? kt + 1 : ktmax_blk;
        stage((kt + 1) & 1, nxt * 64);
        asm volatile("s_waitcnt vmcnt(4)" ::: "memory"); // cur tile's 4 done; next's stay in flight
        __builtin_amdgcn_s_barrier();
        __builtin_amdgcn_sched_barrier(0);

        if (kt <= ktmax_w) {
            const unsigned short* Kb = Kl[kt & 1];
            const unsigned short* Vb = Vl[kt & 1];
            int c0 = kt * 64;

            // K fragments (shared by both q-frags): t=0..3, swizzled chunks g and g+4
            short8 kf0[4], kf1[4];
            #pragma unroll
            for (int t = 0; t < 4; ++t) {
                int r = t * 16 + lr;
                kf0[t] = *reinterpret_cast<const short8*>(Kb + r * 64 + ((g ^ (r & 7)) * 8));
                kf1[t] = *reinterpret_cast<const short8*>(Kb + r * 64 + (((g + 4) ^ (r & 7)) * 8));
            }

            floatx4 stA[4], stB[4];
            #pragma unroll
            for (int t = 0; t < 4; ++t) {
                floatx4 z = (floatx4)(0.f);
                z = __builtin_amdgcn_mfma_f32_16x16x32_bf16(kf0[t], qA0, z, 0, 0, 0);
                stA[t] = __builtin_amdgcn_mfma_f32_16x16x32_bf16(kf1[t], qA1, z, 0, 0, 0);
                floatx4 y = (floatx4)(0.f);
                y = __builtin_amdgcn_mfma_f32_16x16x32_bf16(kf0[t], qB0, y, 0, 0, 0);
                stB[t] = __builtin_amdgcn_mfma_f32_16x16x32_bf16(kf1[t], qB1, y, 0, 0, 0);
            }

            if (kt == ktmax_w) {
                #pragma unroll
                for (int t = 0; t < 4; ++t)
                    #pragma unroll
                    for (int r = 0; r < 4; ++r) {
                        int kc = c0 + t * 16 + g * 4 + r;
                        if (kc > q0) stA[t][r] = -1e30f;
                        if (kc > q0 + 16) stB[t][r] = -1e30f;
                    }
            }

            // ---- softmax frag A ----
            unsigned int uloA[4], uhiA[4], uloB[4], uhiB[4];
            {
                float tm = stA[0][0];
                #pragma unroll
                for (int t = 0; t < 4; ++t)
                    #pragma unroll
                    for (int r = 0; r < 4; ++r) tm = fmaxf(tm, stA[t][r]);
                tm = fmaxf(tm, __shfl_xor(tm, 16));
                tm = fmaxf(tm, __shfl_xor(tm, 32));
                float mn = fmaxf(mA, tm);
                float alpha = __expf(mA - mn);
                float rs = 0.f;
                #pragma unroll
                for (int t = 0; t < 4; ++t) {
                    float e0 = __expf(stA[t][0] - mn), e1 = __expf(stA[t][1] - mn);
                    float e2 = __expf(stA[t][2] - mn), e3 = __expf(stA[t][3] - mn);
                    rs += (e0 + e1) + (e2 + e3);
                    uloA[t] = cvt_pk_bf16(e0, e1);
                    uhiA[t] = cvt_pk_bf16(e2, e3);
                }
                rs += __shfl_xor(rs, 16);
                rs += __shfl_xor(rs, 32);
                mA = mn; lA = lA * alpha + rs;
                #pragma unroll
                for (int db = 0; db < 4; ++db) accA[db] *= alpha;
            }
            // ---- softmax frag B ----
            {
                float tm = stB[0][0];
                #pragma unroll
                for (int t = 0; t < 4; ++t)
                    #pragma unroll
                    for (int r = 0; r < 4; ++r) tm = fmaxf(tm, stB[t][r]);
                tm = fmaxf(tm, __shfl_xor(tm, 16));
                tm = fmaxf(tm, __shfl_xor(tm, 32));
                float mn = fmaxf(mB, tm);
                float alpha = __expf(mB - mn);
                float rs = 0.f;
                #pragma unroll
                for (int t = 0; t < 4; ++t) {
                    float e0 = __expf(stB[t][0] - mn), e1 = __expf(stB[t][1] - mn);
                    float e2 = __expf(stB[t][2] - mn), e3 = __expf(stB[t][3] - mn);
                    rs += (e0 + e1) + (e2 + e3);
                    uloB[t] = cvt_pk_bf16(e0, e1);
                    uhiB[t] = cvt_pk_bf16(e2, e3);
                }
                rs += __shfl_xor(rs, 16);
                rs += __shfl_xor(rs, 32);
                mB = mn; lB = lB * alpha + rs;
                #pragma unroll
                for (int db = 0; db < 4; ++db) accB[db] *= alpha;
            }

            // ---- PV: two 32-key steps; V A-frags shared across q-frags ----
            #pragma unroll
            for (int ks = 0; ks < 2; ++ks) {
                unsigned int a0 = __shfl((int)uloA[ks * 2], src0), b0 = __shfl((int)uloA[ks * 2 + 1], src0);
                unsigned int a1 = __shfl((int)uhiA[ks * 2], src0), b1 = __shfl((int)uhiA[ks * 2 + 1], src0);
                unsigned int a2 = __shfl((int)uloA[ks * 2], src1), b2 = __shfl((int)uloA[ks * 2 + 1], src1);
                unsigned int a3 = __shfl((int)uhiA[ks * 2], src1), b3 = __shfl((int)uhiA[ks * 2 + 1], src1);
                union { unsigned int u[4]; short8 s; } pA;
                pA.u[0] = hi_t ? b0 : a0;
                pA.u[1] = hi_t ? b1 : a1;
                pA.u[2] = hi_t ? b2 : a2;
                pA.u[3] = hi_t ? b3 : a3;
                unsigned int c0s = __shfl((int)uloB[ks * 2], src0), d0 = __shfl((int)uloB[ks * 2 + 1], src0);
                unsigned int c1s = __shfl((int)uhiB[ks * 2], src0), d1 = __shfl((int)uhiB[ks * 2 + 1], src0);
                unsigned int c2s = __shfl((int)uloB[ks * 2], src1), d2 = __shfl((int)uloB[ks * 2 + 1], src1);
                unsigned int c3s = __shfl((int)uhiB[ks * 2], src1), d3 = __shfl((int)uhiB[ks * 2 + 1], src1);
                union { unsigned int u[4]; short8 s; } pB;
                pB.u[0] = hi_t ? d0 : c0s;
                pB.u[1] = hi_t ? d1 : c1s;
                pB.u[2] = hi_t ? d2 : c2s;
                pB.u[3] = hi_t ? d3 : c3s;
                #pragma unroll
                for (int db = 0; db < 4; ++db) {
                    int r = db * 16 + lr;
                    short8 vf = *reinterpret_cast<const short8*>(
                        Vb + r * 64 + (((ks * 4 + g) ^ (r & 7)) * 8));
                    accA[db] = __builtin_amdgcn_mfma_f32_16x16x32_bf16(vf, pA.s, accA[db], 0, 0, 0);
                    accB[db] = __builtin_amdgcn_mfma_f32_16x16x32_bf16(vf, pB.s, accB[db], 0, 0, 0);
                }
            }
        }
        __builtin_amdgcn_sched_barrier(0);
        __builtin_amdgcn_s_barrier();
    }

    float invA = 1.0f / lA, invB = 1.0f / lB;
    unsigned short* Op0 = O + (size_t)q0 * HID + h * 64;
    unsigned short* Op1 = Op0 + (size_t)16 * HID;
    #pragma unroll
    for (int db = 0; db < 4; ++db) {
        int d0 = db * 16 + g * 4;
        *reinterpret_cast<unsigned int*>(Op0 + d0)     = cvt_pk_bf16(accA[db][0] * invA, accA[db][1] * invA);
        *reinterpret_cast<unsigned int*>(Op0 + d0 + 2) = cvt_pk_bf16(accA[db][2] * invA, accA[db][3] * invA);
        *reinterpret_cast<unsigned int*>(Op1 + d0)     = cvt_pk_bf16(accB[db][0] * invB, accB[db][1] * invB);
        *reinterpret_cast<unsigned int*>(Op1 + d0 + 2) = cvt_pk_bf16(accB[db][2] * invB, accB[db][3] * invB);
    }
}

extern "C" void kernel_launch(void* const* d_in, const int* in_sizes, int n_in,
                              void* d_out, int out_size, void* d_ws, size_t ws_size,
                              hipStream_t stream) {
    const int S = 2048, HID = 2048, KVD = 512, NQKV = 3072;
    const float* hs = (const float*)d_in[0];
    const float* Wq = (const float*)d_in[1];
    const float* Wk = (const float*)d_in[2];
    const float* Wv = (const float*)d_in[3];
    const float* Wo = (const float*)d_in[4];
    const int* pos  = (const int*)d_in[5];

    char* base = (char*)d_ws;
    auto alloc = [&](size_t bytes) {
        char* r = base;
        base += (bytes + 255) & ~(size_t)255;
        return r;
    };
    unsigned short* hs_b     = (unsigned short*)alloc((size_t)S * HID * 2);
    unsigned short* Wqkv     = (unsigned short*)alloc((size_t)NQKV * HID * 2);
    unsigned short* WoT      = (unsigned short*)alloc((size_t)HID * HID * 2);
    unsigned short* qkv      = (unsigned short*)alloc((size_t)S * NQKV * 2);
    unsigned short* vT       = (unsigned short*)alloc((size_t)KVD * S * 2);
    unsigned short* attn_out = (unsigned short*)alloc((size_t)S * HID * 2);

    cast_kernel<<<(S * HID / 4 + 255) / 256, 256, 0, stream>>>(hs, hs_b, S * HID);

    transpose_to_bf16<float><<<dim3(HID / 64, HID / 64), 256, 0, stream>>>(Wq, Wqkv, HID, HID);
    transpose_to_bf16<float><<<dim3(KVD / 64, HID / 64), 256, 0, stream>>>(Wk, Wqkv + (size_t)2048 * HID, KVD, HID);
    transpose_to_bf16<float><<<dim3(KVD / 64, HID / 64), 256, 0, stream>>>(Wv, Wqkv + (size_t)2560 * HID, KVD, HID);
    transpose_to_bf16<float><<<dim3(HID / 64, HID / 64), 256, 0, stream>>>(Wo, WoT, HID, HID);

    gemm128<0><<<dim3(NQKV / 128, S / 128), 256, 0, stream>>>(hs_b, Wqkv, qkv, S, NQKV, HID);

    rope_kernel<<<(S * 32 * 32) / 256, 256, 0, stream>>>(qkv, pos, 32, NQKV, 0.125f);
    rope_kernel<<<(S * 8 * 32) / 256, 256, 0, stream>>>(qkv + 2048, pos, 8, NQKV, 1.0f);

    transpose_to_bf16<unsigned short><<<dim3(KVD / 64, S / 64), 256, 0, stream>>>(qkv + 2560, vT, NQKV, S);

    // attention: 512 blocks (32 heads x 16 q-bands of 128 rows), heavy bands first
    attn_kernel<<<512, 256, 0, stream>>>(qkv, vT, attn_out);

    gemm128<1><<<dim3(HID / 128, S / 128), 256, 0, stream>>>(attn_out, WoT, (float*)d_out, S, HID, HID);
}

// Round 4
// 189.349 us; speedup vs baseline: 3.3729x; 1.0223x over previous
//
#include <hip/hip_runtime.h>
#include <stdint.h>

typedef __attribute__((ext_vector_type(8))) short short8;
typedef __attribute__((ext_vector_type(4))) float floatx4;

__device__ __forceinline__ float b2f(unsigned short u) {
    union { unsigned int i; float f; } x; x.i = ((unsigned int)u) << 16; return x.f;
}
__device__ __forceinline__ unsigned short f2b(float f) {
    unsigned int x = __float_as_uint(f);
    return (unsigned short)((x + 0x7FFFu + ((x >> 16) & 1u)) >> 16);
}
__device__ __forceinline__ unsigned int cvt_pk_bf16(float lo, float hi) {
    unsigned int r;
    asm("v_cvt_pk_bf16_f32 %0, %1, %2" : "=v"(r) : "v"(lo), "v"(hi));
    return r;
}
// 2^x in one instruction
__device__ __forceinline__ float exp2_(float x) {
    float r;
    asm("v_exp_f32 %0, %1" : "=v"(r) : "v"(x));
    return r;
}

__device__ __forceinline__ float ldf(const float* p) { return *p; }
__device__ __forceinline__ float ldf(const unsigned short* p) { return b2f(*p); }

__device__ __forceinline__ void gload_lds16(const void* g, void* l) {
    __builtin_amdgcn_global_load_lds((const __attribute__((address_space(1))) unsigned int*)g,
                                     (__attribute__((address_space(3))) unsigned int*)l, 16, 0, 0);
}

// ---------------- cast f32 -> bf16 ----------------
__global__ void cast_kernel(const float* __restrict__ in, unsigned short* __restrict__ out, int n) {
    int i = (blockIdx.x * blockDim.x + threadIdx.x) * 4;
    if (i + 3 < n) {
        float4 v = *reinterpret_cast<const float4*>(in + i);
        out[i + 0] = f2b(v.x);
        out[i + 1] = f2b(v.y);
        out[i + 2] = f2b(v.z);
        out[i + 3] = f2b(v.w);
    }
}

// ---------------- transpose: out[c][r] = in[r][c], bf16 out, strided ----------------
template<typename T>
__global__ void transpose_to_bf16(const T* __restrict__ in, unsigned short* __restrict__ out,
                                  int ld_in, int ld_out) {
    __shared__ float tile[64][65];
    int tx = threadIdx.x & 63, ty = threadIdx.x >> 6;
    int c0 = blockIdx.x * 64, r0 = blockIdx.y * 64;
    #pragma unroll
    for (int i = 0; i < 64; i += 4)
        tile[ty + i][tx] = ldf(&in[(size_t)(r0 + ty + i) * ld_in + c0 + tx]);
    __syncthreads();
    #pragma unroll
    for (int i = 0; i < 64; i += 4)
        out[(size_t)(c0 + ty + i) * ld_out + r0 + tx] = f2b(tile[tx][ty + i]);
}

// ---------------- GEMM: C[M][N] = A[M][K] @ BT[N][K]^T, double-buffered 2-phase ----------------
// 128x128 tile, BK=32, 4 waves (2x2), 4x4 frags/wave. Counted vmcnt(4): next tile's
// global_load_lds stay in flight across the barrier while current tile computes.
template<int OF32>
__global__ __launch_bounds__(256)
void gemm128(const unsigned short* __restrict__ A, const unsigned short* __restrict__ BT,
             void* __restrict__ Cout, int M, int N, int K) {
    __shared__ unsigned short As[2][128 * 32];
    __shared__ unsigned short Bs[2][128 * 32];
    int tid = threadIdx.x;
    int l = tid & 63, w = tid >> 6;
    int lr = l & 15, lg = l >> 4;
    int nb = blockIdx.x * 128, mb = blockIdx.y * 128;
    int wr = w >> 1, wc = w & 1;

    floatx4 acc[4][4];
    #pragma unroll
    for (int m = 0; m < 4; ++m)
        #pragma unroll
        for (int n = 0; n < 4; ++n) acc[m][n] = (floatx4)(0.f);

    int c0i = w * 64 + l, c1i = c0i + 256;
    int r0 = c0i >> 2, k0 = (c0i & 3) * 8;
    int r1 = c1i >> 2, k1 = (c1i & 3) * 8;

    const unsigned short* Ag0 = A + (size_t)(mb + r0) * K + k0;
    const unsigned short* Ag1 = A + (size_t)(mb + r1) * K + k1;
    const unsigned short* Bg0 = BT + (size_t)(nb + r0) * K + k0;
    const unsigned short* Bg1 = BT + (size_t)(nb + r1) * K + k1;

    auto stage = [&](int buf, int kb) {
        gload_lds16(Ag0 + kb, &As[buf][c0i * 8]);
        gload_lds16(Ag1 + kb, &As[buf][c1i * 8]);
        gload_lds16(Bg0 + kb, &Bs[buf][c0i * 8]);
        gload_lds16(Bg1 + kb, &Bs[buf][c1i * 8]);
    };

    int nsteps = K >> 5;
    stage(0, 0);
    for (int it = 0; it < nsteps; ++it) {
        int nxt = (it + 1 < nsteps) ? it + 1 : it;
        stage((it + 1) & 1, nxt * 32);
        asm volatile("s_waitcnt vmcnt(4)" ::: "memory"); // cur tile landed; next's 4 in flight
        __builtin_amdgcn_s_barrier();
        __builtin_amdgcn_sched_barrier(0);

        const unsigned short* Ab = &As[it & 1][(wr * 64 + lr) * 32 + lg * 8];
        const unsigned short* Bb = &Bs[it & 1][(wc * 64 + lr) * 32 + lg * 8];
        short8 af[4], bf[4];
        #pragma unroll
        for (int m = 0; m < 4; ++m) af[m] = *reinterpret_cast<const short8*>(Ab + m * 16 * 32);
        #pragma unroll
        for (int n = 0; n < 4; ++n) bf[n] = *reinterpret_cast<const short8*>(Bb + n * 16 * 32);
        #pragma unroll
        for (int m = 0; m < 4; ++m)
            #pragma unroll
            for (int n = 0; n < 4; ++n)
                acc[m][n] = __builtin_amdgcn_mfma_f32_16x16x32_bf16(af[m], bf[n], acc[m][n], 0, 0, 0);
        __builtin_amdgcn_sched_barrier(0);
        __builtin_amdgcn_s_barrier();
    }
    asm volatile("s_waitcnt vmcnt(0)" ::: "memory");

    int orow0 = mb + wr * 64 + lg * 4;
    int ocol0 = nb + wc * 64 + lr;
    if (OF32) {
        float* C = (float*)Cout;
        #pragma unroll
        for (int m = 0; m < 4; ++m)
            #pragma unroll
            for (int n = 0; n < 4; ++n)
                #pragma unroll
                for (int r = 0; r < 4; ++r)
                    C[(size_t)(orow0 + m * 16 + r) * N + ocol0 + n * 16] = acc[m][n][r];
    } else {
        unsigned short* C = (unsigned short*)Cout;
        #pragma unroll
        for (int m = 0; m < 4; ++m)
            #pragma unroll
            for (int n = 0; n < 4; ++n)
                #pragma unroll
                for (int r = 0; r < 4; ++r)
                    C[(size_t)(orow0 + m * 16 + r) * N + ocol0 + n * 16] = f2b(acc[m][n][r]);
    }
}

// ---------------- RoPE in-place ----------------
__global__ void rope_kernel(unsigned short* __restrict__ x, const int* __restrict__ pos_ids,
                            int H, int stride, float scale) {
    int idx = blockIdx.x * blockDim.x + threadIdx.x;
    int i = idx & 31;
    int h = (idx >> 5) % H;
    int s = idx / (32 * H);
    unsigned short* p = x + (size_t)s * stride + h * 64;
    float x1 = b2f(p[i]), x2 = b2f(p[i + 32]);
    float pos = (float)pos_ids[s];
    float inv = exp2f(-0.41524101186092029f * (float)i);
    float a = pos * inv;
    float sn, cs;
    __sincosf(a, &sn, &cs);
    p[i]      = f2b((x1 * cs - x2 * sn) * scale);
    p[i + 32] = f2b((x2 * cs + x1 * sn) * scale);
}

// ---------------- causal GQA flash attention v4: paired bands ----------------
// 32 bands of 64 q-rows. Block = (head, pair pi): heavy band 31-pi + light band pi.
// Light band's KV tiles are a strict prefix of heavy's -> staged once, used by both.
// Uniform work: (qbH+1)+(qbL+1) = 33 frag-tile-units per block. 512 blocks, 2/CU.
// Per wave: 16 heavy rows (frag A) + 16 light rows (frag C); K/V frags shared.
// Softmax in exp2 domain (Q pre-scaled by log2e/8); defer-max THR=11.5 (T13).
__global__ __launch_bounds__(256)
void attn_kernel(const unsigned short* __restrict__ QKV, // [2048][3072] bf16 (q|k|v)
                 const unsigned short* __restrict__ VT,  // [512][2048]  bf16
                 unsigned short* __restrict__ O) {       // [2048][2048] bf16
    const int S = 2048, LDQ = 3072, HID = 2048;
    __shared__ __align__(16) unsigned short Kl[2][64 * 64];
    __shared__ __align__(16) unsigned short Vl[2][64 * 64];

    int l = threadIdx.x & 63, w = threadIdx.x >> 6;
    int b = blockIdx.x;
    int h = b & 31;
    int pi = b >> 5;               // 0..15, heavy-first dispatch
    int qbH = 31 - pi, qbL = pi;
    int lr = l & 15, g = l >> 4;
    int kvh = h >> 2;
    int qH = qbH * 64 + w * 16 + lr;
    int qL = qbL * 64 + w * 16 + lr;

    const unsigned short* QrH = QKV + (size_t)qH * LDQ + h * 64;
    const unsigned short* QrL = QKV + (size_t)qL * LDQ + h * 64;
    short8 qA0 = *reinterpret_cast<const short8*>(QrH + g * 8);
    short8 qA1 = *reinterpret_cast<const short8*>(QrH + 32 + g * 8);
    short8 qC0 = *reinterpret_cast<const short8*>(QrL + g * 8);
    short8 qC1 = *reinterpret_cast<const short8*>(QrL + 32 + g * 8);

    // staging: 512 chunks of 8 elems per 64x64 tile; slot XOR-swizzle per row
    int c_0 = w * 64 + l, c_1 = c_0 + 256;
    int row0 = c_0 >> 3, lc0 = (c_0 & 7) ^ (row0 & 7);
    int row1 = c_1 >> 3, lc1 = (c_1 & 7) ^ (row1 & 7);
    const unsigned short* Kg = QKV + 2048 + kvh * 64;
    const unsigned short* Vg = VT + (size_t)(kvh * 64) * S;

    floatx4 accA[4], accC[4];
    #pragma unroll
    for (int db = 0; db < 4; ++db) { accA[db] = (floatx4)(0.f); accC[db] = (floatx4)(0.f); }
    float mA = -1e30f, lA = 0.f, mC = -1e30f, lC = 0.f;

    int src0 = lr + (g & 1) * 32;
    int src1 = src0 + 16;
    bool hi_t = (g >> 1) != 0;

    auto stage = [&](int buf, int c0) {
        gload_lds16(Kg + (size_t)(c0 + row0) * LDQ + lc0 * 8, &Kl[buf][c_0 * 8]);
        gload_lds16(Kg + (size_t)(c0 + row1) * LDQ + lc1 * 8, &Kl[buf][c_1 * 8]);
        gload_lds16(Vg + (size_t)row0 * S + c0 + lc0 * 8, &Vl[buf][c_0 * 8]);
        gload_lds16(Vg + (size_t)row1 * S + c0 + lc1 * 8, &Vl[buf][c_1 * 8]);
    };

    // online softmax for one fragment (exp2 domain, defer-max)
    auto softmax_frag = [&](floatx4* st, float& m, float& lsum, floatx4* acc,
                            unsigned int* ulo, unsigned int* uhi) {
        float tm = st[0][0];
        #pragma unroll
        for (int t = 0; t < 4; ++t)
            #pragma unroll
            for (int r = 0; r < 4; ++r) tm = fmaxf(tm, st[t][r]);
        tm = fmaxf(tm, __shfl_xor(tm, 16));
        tm = fmaxf(tm, __shfl_xor(tm, 32));
        if (!__all(tm <= m + 11.5f)) {
            float mn = fmaxf(m, tm);
            float al = exp2_(m - mn);
            lsum *= al;
            #pragma unroll
            for (int db = 0; db < 4; ++db) acc[db] *= al;
            m = mn;
        }
        float rs = 0.f;
        #pragma unroll
        for (int t = 0; t < 4; ++t) {
            float e0 = exp2_(st[t][0] - m), e1 = exp2_(st[t][1] - m);
            float e2 = exp2_(st[t][2] - m), e3 = exp2_(st[t][3] - m);
            rs += (e0 + e1) + (e2 + e3);
            ulo[t] = cvt_pk_bf16(e0, e1);
            uhi[t] = cvt_pk_bf16(e2, e3);
        }
        rs += __shfl_xor(rs, 16);
        rs += __shfl_xor(rs, 32);
        lsum += rs;
    };

    auto build_p = [&](const unsigned int* ulo, const unsigned int* uhi, int ks) -> short8 {
        unsigned int a0 = __shfl((int)ulo[ks * 2], src0), b0 = __shfl((int)ulo[ks * 2 + 1], src0);
        unsigned int a1 = __shfl((int)uhi[ks * 2], src0), b1 = __shfl((int)uhi[ks * 2 + 1], src0);
        unsigned int a2 = __shfl((int)ulo[ks * 2], src1), b2 = __shfl((int)ulo[ks * 2 + 1], src1);
        unsigned int a3 = __shfl((int)uhi[ks * 2], src1), b3 = __shfl((int)uhi[ks * 2 + 1], src1);
        union { unsigned int u[4]; short8 s; } r;
        r.u[0] = hi_t ? b0 : a0;
        r.u[1] = hi_t ? b1 : a1;
        r.u[2] = hi_t ? b2 : a2;
        r.u[3] = hi_t ? b3 : a3;
        return r.s;
    };

    int ktBlk = qbH; // all waves share the heavy diag tile (64-row bands)
    stage(0, 0);
    for (int kt = 0; kt <= ktBlk; ++kt) {
        int nxt = (kt < ktBlk) ? kt + 1 : ktBlk;
        stage((kt + 1) & 1, nxt * 64);
        asm volatile("s_waitcnt vmcnt(4)" ::: "memory");
        __builtin_amdgcn_s_barrier();
        __builtin_amdgcn_sched_barrier(0);

        const unsigned short* Kb = Kl[kt & 1];
        const unsigned short* Vb = Vl[kt & 1];
        int c0 = kt * 64;
        bool actL = kt <= qbL;

        // K fragments (shared by both bands)
        short8 kf0[4], kf1[4];
        #pragma unroll
        for (int t = 0; t < 4; ++t) {
            int r = t * 16 + lr;
            kf0[t] = *reinterpret_cast<const short8*>(Kb + r * 64 + ((g ^ (r & 7)) * 8));
            kf1[t] = *reinterpret_cast<const short8*>(Kb + r * 64 + (((g + 4) ^ (r & 7)) * 8));
        }

        unsigned int uloA[4], uhiA[4], uloC[4], uhiC[4];
        // ---- heavy band (always active) ----
        {
            floatx4 st[4];
            #pragma unroll
            for (int t = 0; t < 4; ++t) {
                floatx4 z = (floatx4)(0.f);
                z = __builtin_amdgcn_mfma_f32_16x16x32_bf16(kf0[t], qA0, z, 0, 0, 0);
                st[t] = __builtin_amdgcn_mfma_f32_16x16x32_bf16(kf1[t], qA1, z, 0, 0, 0);
            }
            if (kt == qbH) {
                #pragma unroll
                for (int t = 0; t < 4; ++t)
                    #pragma unroll
                    for (int r = 0; r < 4; ++r)
                        if (c0 + t * 16 + g * 4 + r > qH) st[t][r] = -1e30f;
            }
            softmax_frag(st, mA, lA, accA, uloA, uhiA);
        }
        // ---- light band ----
        if (actL) {
            floatx4 st[4];
            #pragma unroll
            for (int t = 0; t < 4; ++t) {
                floatx4 z = (floatx4)(0.f);
                z = __builtin_amdgcn_mfma_f32_16x16x32_bf16(kf0[t], qC0, z, 0, 0, 0);
                st[t] = __builtin_amdgcn_mfma_f32_16x16x32_bf16(kf1[t], qC1, z, 0, 0, 0);
            }
            if (kt == qbL) {
                #pragma unroll
                for (int t = 0; t < 4; ++t)
                    #pragma unroll
                    for (int r = 0; r < 4; ++r)
                        if (c0 + t * 16 + g * 4 + r > qL) st[t][r] = -1e30f;
            }
            softmax_frag(st, mC, lC, accC, uloC, uhiC);
        }

        // ---- PV: V fragments shared across bands ----
        #pragma unroll
        for (int ks = 0; ks < 2; ++ks) {
            short8 pA = build_p(uloA, uhiA, ks);
            short8 pC;
            if (actL) pC = build_p(uloC, uhiC, ks);
            #pragma unroll
            for (int db = 0; db < 4; ++db) {
                int r = db * 16 + lr;
                short8 vf = *reinterpret_cast<const short8*>(
                    Vb + r * 64 + (((ks * 4 + g) ^ (r & 7)) * 8));
                accA[db] = __builtin_amdgcn_mfma_f32_16x16x32_bf16(vf, pA, accA[db], 0, 0, 0);
                if (actL)
                    accC[db] = __builtin_amdgcn_mfma_f32_16x16x32_bf16(vf, pC, accC[db], 0, 0, 0);
            }
        }
        __builtin_amdgcn_sched_barrier(0);
        __builtin_amdgcn_s_barrier();
    }
    asm volatile("s_waitcnt vmcnt(0)" ::: "memory");

    float invA = 1.0f / lA, invC = 1.0f / lC;
    unsigned short* OpH = O + (size_t)qH * HID + h * 64;
    unsigned short* OpL = O + (size_t)qL * HID + h * 64;
    #pragma unroll
    for (int db = 0; db < 4; ++db) {
        int d0 = db * 16 + g * 4;
        *reinterpret_cast<unsigned int*>(OpH + d0)     = cvt_pk_bf16(accA[db][0] * invA, accA[db][1] * invA);
        *reinterpret_cast<unsigned int*>(OpH + d0 + 2) = cvt_pk_bf16(accA[db][2] * invA, accA[db][3] * invA);
        *reinterpret_cast<unsigned int*>(OpL + d0)     = cvt_pk_bf16(accC[db][0] * invC, accC[db][1] * invC);
        *reinterpret_cast<unsigned int*>(OpL + d0 + 2) = cvt_pk_bf16(accC[db][2] * invC, accC[db][3] * invC);
    }
}

extern "C" void kernel_launch(void* const* d_in, const int* in_sizes, int n_in,
                              void* d_out, int out_size, void* d_ws, size_t ws_size,
                              hipStream_t stream) {
    const int S = 2048, HID = 2048, KVD = 512, NQKV = 3072;
    const float* hs = (const float*)d_in[0];
    const float* Wq = (const float*)d_in[1];
    const float* Wk = (const float*)d_in[2];
    const float* Wv = (const float*)d_in[3];
    const float* Wo = (const float*)d_in[4];
    const int* pos  = (const int*)d_in[5];

    char* base = (char*)d_ws;
    auto alloc = [&](size_t bytes) {
        char* r = base;
        base += (bytes + 255) & ~(size_t)255;
        return r;
    };
    unsigned short* hs_b     = (unsigned short*)alloc((size_t)S * HID * 2);
    unsigned short* Wqkv     = (unsigned short*)alloc((size_t)NQKV * HID * 2);
    unsigned short* WoT      = (unsigned short*)alloc((size_t)HID * HID * 2);
    unsigned short* qkv      = (unsigned short*)alloc((size_t)S * NQKV * 2);
    unsigned short* vT       = (unsigned short*)alloc((size_t)KVD * S * 2);
    unsigned short* attn_out = (unsigned short*)alloc((size_t)S * HID * 2);

    cast_kernel<<<(S * HID / 4 + 255) / 256, 256, 0, stream>>>(hs, hs_b, S * HID);

    transpose_to_bf16<float><<<dim3(HID / 64, HID / 64), 256, 0, stream>>>(Wq, Wqkv, HID, HID);
    transpose_to_bf16<float><<<dim3(KVD / 64, HID / 64), 256, 0, stream>>>(Wk, Wqkv + (size_t)2048 * HID, KVD, HID);
    transpose_to_bf16<float><<<dim3(KVD / 64, HID / 64), 256, 0, stream>>>(Wv, Wqkv + (size_t)2560 * HID, KVD, HID);
    transpose_to_bf16<float><<<dim3(HID / 64, HID / 64), 256, 0, stream>>>(Wo, WoT, HID, HID);

    gemm128<0><<<dim3(NQKV / 128, S / 128), 256, 0, stream>>>(hs_b, Wqkv, qkv, S, NQKV, HID);

    // Q scaled by (1/8)*log2(e) -> softmax runs in exp2 domain
    rope_kernel<<<(S * 32 * 32) / 256, 256, 0, stream>>>(qkv, pos, 32, NQKV, 0.18033688011112042f);
    rope_kernel<<<(S * 8 * 32) / 256, 256, 0, stream>>>(qkv + 2048, pos, 8, NQKV, 1.0f);

    transpose_to_bf16<unsigned short><<<dim3(KVD / 64, S / 64), 256, 0, stream>>>(qkv + 2560, vT, NQKV, S);

    // attention: 512 blocks = 32 heads x 16 band-pairs (heavy band first in dispatch order)
    attn_kernel<<<512, 256, 0, stream>>>(qkv, vT, attn_out);

    gemm128<1><<<dim3(HID / 128, S / 128), 256, 0, stream>>>(attn_out, WoT, (float*)d_out, S, HID, HID);
}

// Round 5
// 149.957 us; speedup vs baseline: 4.2590x; 1.2627x over previous
//
#include <hip/hip_runtime.h>
#include <stdint.h>

typedef __attribute__((ext_vector_type(8))) short short8;
typedef __attribute__((ext_vector_type(4))) float floatx4;

__device__ __forceinline__ float b2f(unsigned short u) {
    union { unsigned int i; float f; } x; x.i = ((unsigned int)u) << 16; return x.f;
}
__device__ __forceinline__ unsigned short f2b(float f) {
    unsigned int x = __float_as_uint(f);
    return (unsigned short)((x + 0x7FFFu + ((x >> 16) & 1u)) >> 16);
}
__device__ __forceinline__ unsigned int cvt_pk_bf16(float lo, float hi) {
    unsigned int r;
    asm("v_cvt_pk_bf16_f32 %0, %1, %2" : "=v"(r) : "v"(lo), "v"(hi));
    return r;
}
__device__ __forceinline__ float exp2_(float x) {
    float r;
    asm("v_exp_f32 %0, %1" : "=v"(r) : "v"(x));
    return r;
}

__device__ __forceinline__ float ldf(const float* p) { return *p; }
__device__ __forceinline__ float ldf(const unsigned short* p) { return b2f(*p); }

__device__ __forceinline__ void gload_lds16(const void* g, void* l) {
    __builtin_amdgcn_global_load_lds((const __attribute__((address_space(1))) unsigned int*)g,
                                     (__attribute__((address_space(3))) unsigned int*)l, 16, 0, 0);
}

// ---------------- cast f32 -> bf16 ----------------
__global__ void cast_kernel(const float* __restrict__ in, unsigned short* __restrict__ out, int n) {
    int i = (blockIdx.x * blockDim.x + threadIdx.x) * 4;
    if (i + 3 < n) {
        float4 v = *reinterpret_cast<const float4*>(in + i);
        out[i + 0] = f2b(v.x);
        out[i + 1] = f2b(v.y);
        out[i + 2] = f2b(v.z);
        out[i + 3] = f2b(v.w);
    }
}

// ---------------- transpose: out[c][r] = in[r][c], bf16 out, strided ----------------
template<typename T>
__global__ void transpose_to_bf16(const T* __restrict__ in, unsigned short* __restrict__ out,
                                  int ld_in, int ld_out) {
    __shared__ float tile[64][65];
    int tx = threadIdx.x & 63, ty = threadIdx.x >> 6;
    int c0 = blockIdx.x * 64, r0 = blockIdx.y * 64;
    #pragma unroll
    for (int i = 0; i < 64; i += 4)
        tile[ty + i][tx] = ldf(&in[(size_t)(r0 + ty + i) * ld_in + c0 + tx]);
    __syncthreads();
    #pragma unroll
    for (int i = 0; i < 64; i += 4)
        out[(size_t)(c0 + ty + i) * ld_out + r0 + tx] = f2b(tile[tx][ty + i]);
}

// ---------------- GEMM v2: C[M][N] = A[M][K] @ BT[N][K]^T ----------------
// 64(M)x128(N) tile, BK=64, 4 waves (wave tile 64x32 = 4x2 frags).
// LDS rows of 64 elems (128B), slot^(row&7) XOR swizzle -> conflict-free ds_read_b128
// (staged via pre-swizzled global source, linear LDS dest). Double-buffered, counted
// vmcnt(6). Grid XCD-swizzled (requires nwg % 8 == 0).
template<int OF32>
__global__ __launch_bounds__(256)
void gemm64x128(const unsigned short* __restrict__ A, const unsigned short* __restrict__ BT,
                void* __restrict__ Cout, int M, int N, int K) {
    __shared__ __align__(16) unsigned short As[2][64 * 64];
    __shared__ __align__(16) unsigned short Bs[2][128 * 64];
    int tid = threadIdx.x;
    int l = tid & 63, w = tid >> 6;
    int lr = l & 15, lg = l >> 4;

    int gx = gridDim.x;
    int nwg = gx * gridDim.y;
    int flat = blockIdx.y * gx + blockIdx.x;
    int q8 = nwg >> 3;
    int f2 = (flat & 7) * q8 + (flat >> 3); // bijective XCD swizzle (nwg%8==0)
    int bx = f2 % gx, by = f2 / gx;
    int nb = bx * 128, mb = by * 64;

    floatx4 acc[4][2];
    #pragma unroll
    for (int m = 0; m < 4; ++m)
        #pragma unroll
        for (int f = 0; f < 2; ++f) acc[m][f] = (floatx4)(0.f);

    // staging: A chunks tid, tid+256 (512 = 64 rows x 8 slots); B chunks tid+256i (1024)
    int ca1 = tid + 256;
    int ra0 = tid >> 3, ja0 = (tid & 7) ^ (ra0 & 7);
    int ra1 = ca1 >> 3, ja1 = (ca1 & 7) ^ (ra1 & 7);
    const unsigned short* Ag0 = A + (size_t)(mb + ra0) * K + ja0 * 8;
    const unsigned short* Ag1 = A + (size_t)(mb + ra1) * K + ja1 * 8;
    const unsigned short* Bg[4];
    #pragma unroll
    for (int i = 0; i < 4; ++i) {
        int c = tid + 256 * i;
        int r = c >> 3, j = (c & 7) ^ (r & 7);
        Bg[i] = BT + (size_t)(nb + r) * K + j * 8;
    }

    auto stage = [&](int buf, int kb) {
        gload_lds16(Ag0 + kb, &As[buf][tid * 8]);
        gload_lds16(Ag1 + kb, &As[buf][ca1 * 8]);
        #pragma unroll
        for (int i = 0; i < 4; ++i)
            gload_lds16(Bg[i] + kb, &Bs[buf][(tid + 256 * i) * 8]);
    };

    int nsteps = K >> 6;
    stage(0, 0);
    for (int it = 0; it < nsteps; ++it) {
        int nxt = (it + 1 < nsteps) ? it + 1 : it;
        stage((it + 1) & 1, nxt * 64);
        asm volatile("s_waitcnt vmcnt(6)" ::: "memory"); // cur landed; next 6 in flight
        __builtin_amdgcn_s_barrier();
        __builtin_amdgcn_sched_barrier(0);

        const unsigned short* Ab = As[it & 1];
        const unsigned short* Bb = Bs[it & 1];
        #pragma unroll
        for (int kh = 0; kh < 2; ++kh) {
            int sl = ((kh * 4 + lg) ^ (lr & 7)) * 8;
            short8 af[4], bf[2];
            #pragma unroll
            for (int m = 0; m < 4; ++m)
                af[m] = *reinterpret_cast<const short8*>(Ab + (m * 16 + lr) * 64 + sl);
            #pragma unroll
            for (int f = 0; f < 2; ++f)
                bf[f] = *reinterpret_cast<const short8*>(Bb + (w * 32 + f * 16 + lr) * 64 + sl);
            #pragma unroll
            for (int m = 0; m < 4; ++m)
                #pragma unroll
                for (int f = 0; f < 2; ++f)
                    acc[m][f] = __builtin_amdgcn_mfma_f32_16x16x32_bf16(af[m], bf[f], acc[m][f], 0, 0, 0);
        }
        __builtin_amdgcn_sched_barrier(0);
        __builtin_amdgcn_s_barrier();
    }
    asm volatile("s_waitcnt vmcnt(0)" ::: "memory");

    #pragma unroll
    for (int m = 0; m < 4; ++m) {
        int orow = mb + m * 16 + lg * 4;
        #pragma unroll
        for (int f = 0; f < 2; ++f) {
            int ocol = nb + w * 32 + f * 16 + lr;
            #pragma unroll
            for (int r = 0; r < 4; ++r) {
                if (OF32)
                    ((float*)Cout)[(size_t)(orow + r) * N + ocol] = acc[m][f][r];
                else
                    ((unsigned short*)Cout)[(size_t)(orow + r) * N + ocol] = f2b(acc[m][f][r]);
            }
        }
    }
}

// ---------------- RoPE in-place ----------------
__global__ void rope_kernel(unsigned short* __restrict__ x, const int* __restrict__ pos_ids,
                            int H, int stride, float scale) {
    int idx = blockIdx.x * blockDim.x + threadIdx.x;
    int i = idx & 31;
    int h = (idx >> 5) % H;
    int s = idx / (32 * H);
    unsigned short* p = x + (size_t)s * stride + h * 64;
    float x1 = b2f(p[i]), x2 = b2f(p[i + 32]);
    float pos = (float)pos_ids[s];
    float inv = exp2f(-0.41524101186092029f * (float)i);
    float a = pos * inv;
    float sn, cs;
    __sincosf(a, &sn, &cs);
    p[i]      = f2b((x1 * cs - x2 * sn) * scale);
    p[i + 32] = f2b((x2 * cs + x1 * sn) * scale);
}

// ---------------- causal GQA flash attention v5: sequential-pair, uniform 33 iters ----------------
// Block = (head, pi): heavy band qbH=31-pi (64 rows) then light band qbL=pi.
// Iter j<=qbH: heavy tile j; else light tile j-qbH-1 -> EXACTLY 33 iterations per block,
// one 16-row fragment per wave per iteration. All blocks identical work -> no tail.
// KV tiles 64 double-buffered LDS (XOR-swizzled), counted vmcnt(4).
// Softmax in exp2 domain (Q pre-scaled by log2e/8); defer-max THR=11.5.
__global__ __launch_bounds__(256)
void attn_kernel(const unsigned short* __restrict__ QKV, // [2048][3072] bf16 (q|k|v)
                 const unsigned short* __restrict__ VT,  // [512][2048]  bf16
                 unsigned short* __restrict__ O) {       // [2048][2048] bf16
    const int S = 2048, LDQ = 3072, HID = 2048;
    __shared__ __align__(16) unsigned short Kl[2][64 * 64];
    __shared__ __align__(16) unsigned short Vl[2][64 * 64];

    int l = threadIdx.x & 63, w = threadIdx.x >> 6;
    int b = blockIdx.x;
    int h = b & 31;
    int pi = b >> 5;
    int qbH = 31 - pi, qbL = pi;
    int lr = l & 15, g = l >> 4;
    int kvh = h >> 2;
    int qH = qbH * 64 + w * 16 + lr;
    int qL = qbL * 64 + w * 16 + lr;

    const unsigned short* QrH = QKV + (size_t)qH * LDQ + h * 64;
    const unsigned short* QrL = QKV + (size_t)qL * LDQ + h * 64;
    short8 qA0 = *reinterpret_cast<const short8*>(QrH + g * 8);
    short8 qA1 = *reinterpret_cast<const short8*>(QrH + 32 + g * 8);
    short8 qC0 = *reinterpret_cast<const short8*>(QrL + g * 8);
    short8 qC1 = *reinterpret_cast<const short8*>(QrL + 32 + g * 8);

    int c_0 = w * 64 + l, c_1 = c_0 + 256;
    int row0 = c_0 >> 3, lc0 = (c_0 & 7) ^ (row0 & 7);
    int row1 = c_1 >> 3, lc1 = (c_1 & 7) ^ (row1 & 7);
    const unsigned short* Kg = QKV + 2048 + kvh * 64;
    const unsigned short* Vg = VT + (size_t)(kvh * 64) * S;

    floatx4 accA[4], accC[4];
    #pragma unroll
    for (int db = 0; db < 4; ++db) { accA[db] = (floatx4)(0.f); accC[db] = (floatx4)(0.f); }
    float mA = -1e30f, lA = 0.f, mC = -1e30f, lC = 0.f;

    int src0 = lr + (g & 1) * 32;
    int src1 = src0 + 16;
    bool hi_t = (g >> 1) != 0;

    auto stage = [&](int buf, int c0) {
        gload_lds16(Kg + (size_t)(c0 + row0) * LDQ + lc0 * 8, &Kl[buf][c_0 * 8]);
        gload_lds16(Kg + (size_t)(c0 + row1) * LDQ + lc1 * 8, &Kl[buf][c_1 * 8]);
        gload_lds16(Vg + (size_t)row0 * S + c0 + lc0 * 8, &Vl[buf][c_0 * 8]);
        gload_lds16(Vg + (size_t)row1 * S + c0 + lc1 * 8, &Vl[buf][c_1 * 8]);
    };

    auto build_p = [&](const unsigned int* ulo, const unsigned int* uhi, int ks) -> short8 {
        unsigned int a0 = __shfl((int)ulo[ks * 2], src0), b0 = __shfl((int)ulo[ks * 2 + 1], src0);
        unsigned int a1 = __shfl((int)uhi[ks * 2], src0), b1 = __shfl((int)uhi[ks * 2 + 1], src0);
        unsigned int a2 = __shfl((int)ulo[ks * 2], src1), b2 = __shfl((int)ulo[ks * 2 + 1], src1);
        unsigned int a3 = __shfl((int)uhi[ks * 2], src1), b3 = __shfl((int)uhi[ks * 2 + 1], src1);
        union { unsigned int u[4]; short8 s; } r;
        r.u[0] = hi_t ? b0 : a0;
        r.u[1] = hi_t ? b1 : a1;
        r.u[2] = hi_t ? b2 : a2;
        r.u[3] = hi_t ? b3 : a3;
        return r.s;
    };

    // process one fragment against tile at c0
    auto process = [&](const unsigned short* Kb, const unsigned short* Vb, int c0,
                       short8 q0, short8 q1, int qrow, bool diag,
                       float& m, float& lsum, floatx4* acc) {
        short8 kf0[4], kf1[4];
        #pragma unroll
        for (int t = 0; t < 4; ++t) {
            int r = t * 16 + lr;
            kf0[t] = *reinterpret_cast<const short8*>(Kb + r * 64 + ((g ^ (r & 7)) * 8));
            kf1[t] = *reinterpret_cast<const short8*>(Kb + r * 64 + (((g + 4) ^ (r & 7)) * 8));
        }
        floatx4 st[4];
        #pragma unroll
        for (int t = 0; t < 4; ++t) {
            floatx4 z = (floatx4)(0.f);
            z = __builtin_amdgcn_mfma_f32_16x16x32_bf16(kf0[t], q0, z, 0, 0, 0);
            st[t] = __builtin_amdgcn_mfma_f32_16x16x32_bf16(kf1[t], q1, z, 0, 0, 0);
        }
        if (diag) {
            #pragma unroll
            for (int t = 0; t < 4; ++t)
                #pragma unroll
                for (int r = 0; r < 4; ++r)
                    if (c0 + t * 16 + g * 4 + r > qrow) st[t][r] = -1e30f;
        }
        // pairwise max tree (depth 4) + 2 cross-group reductions
        float tt[4];
        #pragma unroll
        for (int t = 0; t < 4; ++t)
            tt[t] = fmaxf(fmaxf(st[t][0], st[t][1]), fmaxf(st[t][2], st[t][3]));
        float tm = fmaxf(fmaxf(tt[0], tt[1]), fmaxf(tt[2], tt[3]));
        tm = fmaxf(tm, __shfl_xor(tm, 16));
        tm = fmaxf(tm, __shfl_xor(tm, 32));
        if (!__all(tm <= m + 11.5f)) {
            float mn = fmaxf(m, tm);
            float al = exp2_(m - mn);
            lsum *= al;
            #pragma unroll
            for (int db = 0; db < 4; ++db) acc[db] *= al;
            m = mn;
        }
        unsigned int ulo[4], uhi[4];
        float rs = 0.f;
        #pragma unroll
        for (int t = 0; t < 4; ++t) {
            float e0 = exp2_(st[t][0] - m), e1 = exp2_(st[t][1] - m);
            float e2 = exp2_(st[t][2] - m), e3 = exp2_(st[t][3] - m);
            rs += (e0 + e1) + (e2 + e3);
            ulo[t] = cvt_pk_bf16(e0, e1);
            uhi[t] = cvt_pk_bf16(e2, e3);
        }
        rs += __shfl_xor(rs, 16);
        rs += __shfl_xor(rs, 32);
        lsum += rs;
        #pragma unroll
        for (int ks = 0; ks < 2; ++ks) {
            short8 pf = build_p(ulo, uhi, ks);
            #pragma unroll
            for (int db = 0; db < 4; ++db) {
                int r = db * 16 + lr;
                short8 vf = *reinterpret_cast<const short8*>(
                    Vb + r * 64 + (((ks * 4 + g) ^ (r & 7)) * 8));
                acc[db] = __builtin_amdgcn_mfma_f32_16x16x32_bf16(vf, pf, acc[db], 0, 0, 0);
            }
        }
    };

    stage(0, 0);
    for (int j = 0; j < 33; ++j) {
        int jn = (j < 32) ? j + 1 : 32;
        int tn = (jn <= qbH) ? jn : jn - qbH - 1;
        stage((j + 1) & 1, tn * 64);
        asm volatile("s_waitcnt vmcnt(4)" ::: "memory");
        __builtin_amdgcn_s_barrier();
        __builtin_amdgcn_sched_barrier(0);

        const unsigned short* Kb = Kl[j & 1];
        const unsigned short* Vb = Vl[j & 1];
        if (j <= qbH)
            process(Kb, Vb, j * 64, qA0, qA1, qH, j == qbH, mA, lA, accA);
        else
            process(Kb, Vb, (j - qbH - 1) * 64, qC0, qC1, qL, j == 32, mC, lC, accC);

        __builtin_amdgcn_sched_barrier(0);
        __builtin_amdgcn_s_barrier();
    }
    asm volatile("s_waitcnt vmcnt(0)" ::: "memory");

    float invA = 1.0f / lA, invC = 1.0f / lC;
    unsigned short* OpH = O + (size_t)qH * HID + h * 64;
    unsigned short* OpL = O + (size_t)qL * HID + h * 64;
    #pragma unroll
    for (int db = 0; db < 4; ++db) {
        int d0 = db * 16 + g * 4;
        *reinterpret_cast<unsigned int*>(OpH + d0)     = cvt_pk_bf16(accA[db][0] * invA, accA[db][1] * invA);
        *reinterpret_cast<unsigned int*>(OpH + d0 + 2) = cvt_pk_bf16(accA[db][2] * invA, accA[db][3] * invA);
        *reinterpret_cast<unsigned int*>(OpL + d0)     = cvt_pk_bf16(accC[db][0] * invC, accC[db][1] * invC);
        *reinterpret_cast<unsigned int*>(OpL + d0 + 2) = cvt_pk_bf16(accC[db][2] * invC, accC[db][3] * invC);
    }
}

extern "C" void kernel_launch(void* const* d_in, const int* in_sizes, int n_in,
                              void* d_out, int out_size, void* d_ws, size_t ws_size,
                              hipStream_t stream) {
    const int S = 2048, HID = 2048, KVD = 512, NQKV = 3072;
    const float* hs = (const float*)d_in[0];
    const float* Wq = (const float*)d_in[1];
    const float* Wk = (const float*)d_in[2];
    const float* Wv = (const float*)d_in[3];
    const float* Wo = (const float*)d_in[4];
    const int* pos  = (const int*)d_in[5];

    char* base = (char*)d_ws;
    auto alloc = [&](size_t bytes) {
        char* r = base;
        base += (bytes + 255) & ~(size_t)255;
        return r;
    };
    unsigned short* hs_b     = (unsigned short*)alloc((size_t)S * HID * 2);
    unsigned short* Wqkv     = (unsigned short*)alloc((size_t)NQKV * HID * 2);
    unsigned short* WoT      = (unsigned short*)alloc((size_t)HID * HID * 2);
    unsigned short* qkv      = (unsigned short*)alloc((size_t)S * NQKV * 2);
    unsigned short* vT       = (unsigned short*)alloc((size_t)KVD * S * 2);
    unsigned short* attn_out = (unsigned short*)alloc((size_t)S * HID * 2);

    cast_kernel<<<(S * HID / 4 + 255) / 256, 256, 0, stream>>>(hs, hs_b, S * HID);

    transpose_to_bf16<float><<<dim3(HID / 64, HID / 64), 256, 0, stream>>>(Wq, Wqkv, HID, HID);
    transpose_to_bf16<float><<<dim3(KVD / 64, HID / 64), 256, 0, stream>>>(Wk, Wqkv + (size_t)2048 * HID, KVD, HID);
    transpose_to_bf16<float><<<dim3(KVD / 64, HID / 64), 256, 0, stream>>>(Wv, Wqkv + (size_t)2560 * HID, KVD, HID);
    transpose_to_bf16<float><<<dim3(HID / 64, HID / 64), 256, 0, stream>>>(Wo, WoT, HID, HID);

    // fused QKV projection: grid 24x32 = 768 blocks (%8==0)
    gemm64x128<0><<<dim3(NQKV / 128, S / 64), 256, 0, stream>>>(hs_b, Wqkv, qkv, S, NQKV, HID);

    // Q scaled by (1/8)*log2(e) -> softmax runs in exp2 domain
    rope_kernel<<<(S * 32 * 32) / 256, 256, 0, stream>>>(qkv, pos, 32, NQKV, 0.18033688011112042f);
    rope_kernel<<<(S * 8 * 32) / 256, 256, 0, stream>>>(qkv + 2048, pos, 8, NQKV, 1.0f);

    transpose_to_bf16<unsigned short><<<dim3(KVD / 64, S / 64), 256, 0, stream>>>(qkv + 2560, vT, NQKV, S);

    // attention: 512 uniform blocks = 32 heads x 16 sequential band-pairs
    attn_kernel<<<512, 256, 0, stream>>>(qkv, vT, attn_out);

    // output projection: grid 16x32 = 512 blocks (%8==0)
    gemm64x128<1><<<dim3(HID / 128, S / 64), 256, 0, stream>>>(attn_out, WoT, (float*)d_out, S, HID, HID);
}